// Round 6
// baseline (292.573 us; speedup 1.0000x reference)
//
#include <hip/hip_runtime.h>

typedef __attribute__((ext_vector_type(4))) float f32x4;
typedef __attribute__((ext_vector_type(8))) short bf16x8;
typedef __attribute__((ext_vector_type(4))) unsigned short u16x4;
typedef unsigned short u16;

#define MFMA16(a, b, c) __builtin_amdgcn_mfma_f32_16x16x32_bf16((a), (b), (c), 0, 0, 0)

#define T_SEQ 2048
#define DMODEL 2048
#define NHEADS 16
#define HDIM 128
#define WINDOW 256
#define MROWS 4096  // B*T
#define SC 0.08838834764831845f  // 1/sqrt(128)

__device__ __forceinline__ u16 f2bf(float f) {
  union { float f; unsigned u; } v; v.f = f;
  return (u16)((v.u + 0x7FFFu + ((v.u >> 16) & 1u)) >> 16);
}
__device__ __forceinline__ float bf2f(u16 u) {
  union { unsigned u; float f; } v; v.u = ((unsigned)u) << 16;
  return v.f;
}
__device__ __forceinline__ void gl_lds16(const u16* g, u16* l) {
  __builtin_amdgcn_global_load_lds((const __attribute__((address_space(1))) void*)(g),
                                   (__attribute__((address_space(3))) void*)(l), 16, 0, 0);
}

// ---------------------------------------------------------------------------
// Convert x, Wq, Wk, Wv, Wo (f32) -> contiguous bf16: [xb NX][wq][wk][wv][wo]
// ---------------------------------------------------------------------------
__global__ __launch_bounds__(256) void convert_all(const float* __restrict__ x,
                                                   const float* __restrict__ wq,
                                                   const float* __restrict__ wk,
                                                   const float* __restrict__ wv,
                                                   const float* __restrict__ wo,
                                                   u16* __restrict__ dst) {
  const size_t NX = (size_t)MROWS * DMODEL;
  const size_t NW = (size_t)DMODEL * DMODEL;
  const size_t chunks = (NX + 4 * NW) / 8;
  for (size_t ci = (size_t)blockIdx.x * 256 + threadIdx.x; ci < chunks;
       ci += (size_t)gridDim.x * 256) {
    const size_t off = ci * 8;
    const float* src;
    size_t so;
    if (off < NX) { src = x; so = off; }
    else {
      size_t rem = off - NX;
      if (rem < NW) { src = wq; so = rem; }
      else if (rem < 2 * NW) { src = wk; so = rem - NW; }
      else if (rem < 3 * NW) { src = wv; so = rem - 2 * NW; }
      else { src = wo; so = rem - 3 * NW; }
    }
    f32x4 a = *(const f32x4*)&src[so];
    f32x4 b = *(const f32x4*)&src[so + 4];
    bf16x8 o;
#pragma unroll
    for (int j = 0; j < 4; ++j) { o[j] = (short)f2bf(a[j]); o[j + 4] = (short)f2bf(b[j]); }
    *(bf16x8*)&dst[off] = o;
  }
}

// ---------------------------------------------------------------------------
// 8-phase (m201-template) QKV GEMM: C[4096,6144] = A @ Wcat^T, all bf16.
// BM=BN=256, BK=64. Grid 384 (16 mt x 24 nt). 512 thr = 8 waves (2m x 4n),
// per-wave 128x64 (8mi x 4ni), 16 MFMA/phase, 8 phases / 2 K-tiles.
// LDS 128 KB = 2 bufs x (A 32K + B 32K), XOR slot-swizzle (slot ^= row&7,
// 16B slots) on read + inverse-permuted gl_lds source (verified 0-conflict).
// One half-tile (16 KB, 2 gl_lds/thread) staged per phase; counted vmcnt(4)
// at phases 4 & 8 only. Staging ledger (iter i, tiles 2i->buf0, 2i+1->buf1):
//   P1:Ah0(2i+1) P2:Ah1(2i+1) P3:Bh0(2i+2) P4:Bh1(2i+2)
//   P5:Ah0(2i+2) P6:Ah1(2i+2) P7:Bh0(2i+3) P8:Bh1(2i+3)
// vmcnt(4)@P4 forces tile 2i+1 (read P5); vmcnt(4)@P8 forces 2i+2 (read P1').
// Epilogue: q,k cols -> qk buffer; v cols -> transposed vt buffer.
// ---------------------------------------------------------------------------
#define QKV_NT 32  // K-tiles (2048/64)

__global__ __launch_bounds__(512, 2) void gemm_qkv(const u16* __restrict__ A,
                                                   const u16* __restrict__ W,
                                                   u16* __restrict__ qk,
                                                   u16* __restrict__ vt) {
  __shared__ u16 lds[65536];  // 128 KB
  const int tid = threadIdx.x, w = tid >> 6, lane = tid & 63;
  const int wm = w >> 2, wn = w & 3;
  const int fr = lane & 15, g = lane >> 4, g4 = g * 4;

  // XCD-aware bijective swizzle: 384 blocks = 8 xcd x 48
  int flat = (blockIdx.x & 7) * 48 + (blockIdx.x >> 3);
  const int mt = flat / 24, nt = flat % 24;
  const int m0 = mt * 256, n0 = nt * 256;

  // frag-read offsets: LDS slot = (kc*4+g) ^ (fr&7), 16B slots, row stride 64 u16
  const int xs0 = (g ^ (fr & 7)) * 8;
  const int xs1 = xs0 ^ 32;
  const int aRow = wm * 128 + fr;
  const int bRow = wn * 64 + fr;

  // staging: load j covers idx=j*512+tid -> (row idx>>3, slot idx&7) of a half;
  // source chunk = (slot ^ (row&7)) (inverse of read swizzle)
  const int idx0 = tid, idx1 = 512 + tid;
  const u16* pA0 = A + (size_t)(m0 + (idx0 >> 3)) * DMODEL + ((idx0 & 7) ^ ((idx0 >> 3) & 7)) * 8;
  const u16* pA1 = A + (size_t)(m0 + (idx1 >> 3)) * DMODEL + ((idx1 & 7) ^ ((idx1 >> 3) & 7)) * 8;
  const u16* pB0 = W + (size_t)(n0 + (idx0 >> 3)) * DMODEL + ((idx0 & 7) ^ ((idx0 >> 3) & 7)) * 8;
  const u16* pB1 = W + (size_t)(n0 + (idx1 >> 3)) * DMODEL + ((idx1 & 7) ^ ((idx1 >> 3) & 7)) * 8;

#define BAR __builtin_amdgcn_s_barrier()
#define FEN asm volatile("" ::: "memory")
#define VMC4 asm volatile("s_waitcnt vmcnt(4)" ::: "memory")
#define VMC0 asm volatile("s_waitcnt vmcnt(0)" ::: "memory")

#define SAH(h, t, c)                                                                   \
  { gl_lds16(pA0 + (size_t)(h) * 128 * DMODEL + (t) * 64,                              \
             &lds[(c) * 32768 + (h) * 8192 + w * 512]);                                \
    gl_lds16(pA1 + (size_t)(h) * 128 * DMODEL + (t) * 64,                              \
             &lds[(c) * 32768 + (h) * 8192 + 4096 + w * 512]); }
#define SBH(h, t, c)                                                                   \
  { gl_lds16(pB0 + (size_t)(h) * 128 * DMODEL + (t) * 64,                              \
             &lds[(c) * 32768 + 16384 + (h) * 8192 + w * 512]);                        \
    gl_lds16(pB1 + (size_t)(h) * 128 * DMODEL + (t) * 64,                              \
             &lds[(c) * 32768 + 16384 + (h) * 8192 + 4096 + w * 512]); }

#define RD_ALO(c)                                                                      \
  { _Pragma("unroll") for (int m_ = 0; m_ < 4; ++m_) {                                 \
      af[m_][0] = *(const bf16x8*)&lds[(c) * 32768 + (aRow + m_ * 16) * 64 + xs0];     \
      af[m_][1] = *(const bf16x8*)&lds[(c) * 32768 + (aRow + m_ * 16) * 64 + xs1]; } }
#define RD_AHI(c)                                                                      \
  { _Pragma("unroll") for (int m_ = 0; m_ < 4; ++m_) {                                 \
      af[m_][0] = *(const bf16x8*)&lds[(c) * 32768 + (aRow + 64 + m_ * 16) * 64 + xs0];\
      af[m_][1] = *(const bf16x8*)&lds[(c) * 32768 + (aRow + 64 + m_ * 16) * 64 + xs1]; } }
#define RD_BLO(c)                                                                      \
  { _Pragma("unroll") for (int n_ = 0; n_ < 2; ++n_) {                                 \
      bfr[n_][0] = *(const bf16x8*)&lds[(c) * 32768 + 16384 + (bRow + n_ * 16) * 64 + xs0]; \
      bfr[n_][1] = *(const bf16x8*)&lds[(c) * 32768 + 16384 + (bRow + n_ * 16) * 64 + xs1]; } }
#define RD_BHI(c)                                                                      \
  { _Pragma("unroll") for (int n_ = 0; n_ < 2; ++n_) {                                 \
      bfr[2 + n_][0] = *(const bf16x8*)&lds[(c) * 32768 + 16384 + (bRow + (2 + n_) * 16) * 64 + xs0]; \
      bfr[2 + n_][1] = *(const bf16x8*)&lds[(c) * 32768 + 16384 + (bRow + (2 + n_) * 16) * 64 + xs1]; } }

#define MMQ(MB, NB)                                                                    \
  { __builtin_amdgcn_s_setprio(1);                                                    \
    _Pragma("unroll") for (int kc_ = 0; kc_ < 2; ++kc_)                                \
      _Pragma("unroll") for (int m_ = 0; m_ < 4; ++m_)                                 \
        _Pragma("unroll") for (int n_ = 0; n_ < 2; ++n_)                               \
          acc[(MB) + m_][(NB) + n_] =                                                  \
              MFMA16(af[m_][kc_], bfr[(NB) + n_][kc_], acc[(MB) + m_][(NB) + n_]);     \
    __builtin_amdgcn_s_setprio(0); }

  bf16x8 af[4][2], bfr[4][2];
  f32x4 acc[8][4];
#pragma unroll
  for (int i = 0; i < 8; ++i)
#pragma unroll
    for (int j = 0; j < 4; ++j) acc[i][j] = (f32x4){0.f, 0.f, 0.f, 0.f};

  // prologue: A(0), B(0) -> buf0; B(1) -> buf1; vmcnt(4) leaves B(1) in flight
  SAH(0, 0, 0); SAH(1, 0, 0);
  SBH(0, 0, 0); SBH(1, 0, 0);
  SBH(0, 1, 1); SBH(1, 1, 1);
  VMC4; BAR;

  for (int i = 0; i < 15; ++i) {
    const int t2 = 2 * i;
    // P1 [tile t2, buf0]
    RD_ALO(0); RD_BLO(0); SAH(0, t2 + 1, 1);
    FEN; BAR; MMQ(0, 0); FEN; BAR;
    // P2
    RD_BHI(0); SAH(1, t2 + 1, 1);
    FEN; BAR; MMQ(0, 2); FEN; BAR;
    // P3
    RD_AHI(0); SBH(0, t2 + 2, 0);
    FEN; BAR; MMQ(4, 0); FEN; BAR;
    // P4
    SBH(1, t2 + 2, 0);
    VMC4; BAR; MMQ(4, 2); FEN; BAR;
    // P5 [tile t2+1, buf1]
    RD_ALO(1); RD_BLO(1); SAH(0, t2 + 2, 0);
    FEN; BAR; MMQ(0, 0); FEN; BAR;
    // P6
    RD_BHI(1); SAH(1, t2 + 2, 0);
    FEN; BAR; MMQ(0, 2); FEN; BAR;
    // P7
    RD_AHI(1); SBH(0, t2 + 3, 1);
    FEN; BAR; MMQ(4, 0); FEN; BAR;
    // P8
    SBH(1, t2 + 3, 1);
    VMC4; BAR; MMQ(4, 2); FEN; BAR;
  }
  // tail: tiles 30 (buf0), 31 (buf1); A(31) still staged P1/P2
  RD_ALO(0); RD_BLO(0); SAH(0, 31, 1);
  FEN; BAR; MMQ(0, 0); FEN; BAR;
  RD_BHI(0); SAH(1, 31, 1);
  FEN; BAR; MMQ(0, 2); FEN; BAR;
  RD_AHI(0);
  FEN; BAR; MMQ(4, 0); FEN; BAR;
  VMC0; BAR; MMQ(4, 2); FEN; BAR;
  RD_ALO(1); RD_BLO(1);
  FEN; BAR; MMQ(0, 0); FEN; BAR;
  RD_BHI(1);
  FEN; BAR; MMQ(0, 2); FEN; BAR;
  RD_AHI(1);
  FEN; BAR; MMQ(4, 0); FEN; BAR;
  MMQ(4, 2);

  // epilogue
#pragma unroll
  for (int mi = 0; mi < 8; ++mi)
#pragma unroll
    for (int ni = 0; ni < 4; ++ni) {
      const int row0 = m0 + wm * 128 + mi * 16 + g4;
      const int cg = n0 + wn * 64 + ni * 16 + fr;
      if (cg < 2 * DMODEL) {
#pragma unroll
        for (int r = 0; r < 4; ++r)
          qk[(size_t)(row0 + r) * (2 * DMODEL) + cg] = f2bf(acc[mi][ni][r]);
      } else {
        const int cc = cg - 2 * DMODEL;
        const int hh = cc >> 7, d = cc & 127;
        const int bb = row0 >> 11, tl = row0 & 2047;
        u16x4 w4;
#pragma unroll
        for (int r = 0; r < 4; ++r) w4[r] = f2bf(acc[mi][ni][r]);
        *(u16x4*)&vt[((size_t)(bb * NHEADS + hh) * HDIM + d) * T_SEQ + tl] = w4;
      }
    }
#undef SAH
#undef SBH
}

// ---------------------------------------------------------------------------
// m97-structure GEMM (out-projection, unchanged known-good). C = A @ W^T, f32.
// ---------------------------------------------------------------------------
#define BM 128
#define BN 128
#define BK 32

__global__ __launch_bounds__(256) void gemm_out(const u16* __restrict__ A,
                                                const u16* __restrict__ W0,
                                                float* __restrict__ outf,
                                                int K) {
  __shared__ u16 As[BM * BK];
  __shared__ u16 Bs[BN * BK];
  const int tid = threadIdx.x, wave = tid >> 6, lane = tid & 63;
  const int fr = lane & 15, ko = (lane >> 4) * 8;
  const int wm = (wave >> 1) * 64, wn = (wave & 1) * 64;

  int flat = blockIdx.y * gridDim.x + blockIdx.x;
  const int nwg = gridDim.x * gridDim.y;
  const int cpx = nwg >> 3;
  flat = (flat & 7) * cpx + (flat >> 3);
  const int m0 = (flat / gridDim.x) * BM;
  const int n0 = (flat % gridDim.x) * BN;

  const int srow = tid >> 2;
  const int scol = (tid & 3) * 8;

  f32x4 acc[4][4];
#pragma unroll
  for (int i = 0; i < 4; ++i)
#pragma unroll
    for (int j = 0; j < 4; ++j) acc[i][j] = (f32x4){0.f, 0.f, 0.f, 0.f};

  for (int k0 = 0; k0 < K; k0 += BK) {
#pragma unroll
    for (int i = 0; i < 2; ++i) {
      const int row = srow + i * 64;
      gl_lds16(&A[(size_t)(m0 + row) * K + k0 + scol], &As[(i * 256 + wave * 64) * 8]);
      gl_lds16(&W0[(size_t)(n0 + row) * K + k0 + scol], &Bs[(i * 256 + wave * 64) * 8]);
    }
    __syncthreads();
    bf16x8 af[4], bfr[4];
#pragma unroll
    for (int i = 0; i < 4; ++i) af[i] = *(const bf16x8*)&As[(wm + i * 16 + fr) * BK + ko];
#pragma unroll
    for (int i = 0; i < 4; ++i) bfr[i] = *(const bf16x8*)&Bs[(wn + i * 16 + fr) * BK + ko];
#pragma unroll
    for (int mi = 0; mi < 4; ++mi)
#pragma unroll
      for (int ni = 0; ni < 4; ++ni)
        acc[mi][ni] = MFMA16(af[mi], bfr[ni], acc[mi][ni]);
    __syncthreads();
  }

#pragma unroll
  for (int mi = 0; mi < 4; ++mi)
#pragma unroll
    for (int ni = 0; ni < 4; ++ni) {
      const int row0 = m0 + wm + mi * 16 + (lane >> 4) * 4;
      const int c = n0 + wn + ni * 16 + fr;
#pragma unroll
      for (int r = 0; r < 4; ++r)
        outf[(size_t)(row0 + r) * DMODEL + c] = acc[mi][ni][r];
    }
}

// ---------------------------------------------------------------------------
// Striped flash attention (unchanged, known-good).
// ---------------------------------------------------------------------------
#define QB 64
#define KVB 64
#define LDK 136
#define LDV 72
#define LDP 80

__global__ __launch_bounds__(256) void attn_kernel(const u16* __restrict__ qk,
                                                   const u16* __restrict__ vt,
                                                   u16* __restrict__ op,
                                                   u16* __restrict__ pO,
                                                   float* __restrict__ pm,
                                                   float* __restrict__ pl) {
  __shared__ u16 Ks[KVB][LDK];
  __shared__ u16 Vs[HDIM][LDV];
  __shared__ u16 Ps[4][16][LDP];

  const int bx = blockIdx.x, h = blockIdx.y, b = blockIdx.z;
  const bool isglobal = (h & 1) == 0;
  int qt, klo, khi, part = 0;
  bool partial = false;
  if (isglobal) {
    const int c = 47 - bx;
    if (c < 16) { qt = c; klo = 0; khi = qt; }
    else {
      qt = 16 + ((c - 16) >> 1);
      part = (c - 16) & 1;
      partial = true;
      if (part == 0) { klo = 0; khi = 15; } else { klo = 16; khi = qt; }
    }
  } else {
    if (bx >= 32) return;
    qt = 31 - bx;
    const int lo_ = qt * QB - (WINDOW - 1);
    klo = lo_ > 0 ? (lo_ >> 6) : 0;
    khi = qt;
  }

  const int tid = threadIdx.x, wave = tid >> 6, lane = tid & 63;
  const int fr = lane & 15, ko = (lane >> 4) * 8, g4 = (lane >> 4) * 4;
  const int q0 = qt * QB;
  const size_t baseq = (size_t)b * T_SEQ * (2 * DMODEL) + (size_t)h * HDIM;
  const size_t basek = baseq + DMODEL;
  const size_t basev = (size_t)(b * NHEADS + h) * HDIM * T_SEQ;
  const size_t baseo = (size_t)b * T_SEQ * DMODEL + (size_t)h * HDIM;

  bf16x8 qf[4];
  {
    const int qrow = q0 + wave * 16 + fr;
#pragma unroll
    for (int ds = 0; ds < 4; ++ds)
      qf[ds] = *(const bf16x8*)&qk[baseq + (size_t)qrow * (2 * DMODEL) + ds * 32 + ko];
  }

  float mrun = -1e30f, lrun = 0.f;
  f32x4 o[8];
#pragma unroll
  for (int dt = 0; dt < 8; ++dt) o[dt] = (f32x4){0.f, 0.f, 0.f, 0.f};

  const int kr = tid >> 4, kc = (tid & 15) * 8;
  const int vr = tid >> 3, vc = (tid & 7) * 8;
  bf16x8 kreg[4], vreg[4];

#define LOADTILE(KT)                                                                      \
  {                                                                                       \
    _Pragma("unroll") for (int it = 0; it < 4; ++it) {                                    \
      kreg[it] = *(const bf16x8*)&qk[basek + (size_t)((KT) * KVB + kr + it * 16) * (2 * DMODEL) + kc]; \
      vreg[it] = *(const bf16x8*)&vt[basev + (size_t)(vr + it * 32) * T_SEQ + (KT) * KVB + vc];        \
    }                                                                                     \
  }
#define WRITETILE()                                                                       \
  {                                                                                       \
    _Pragma("unroll") for (int it = 0; it < 4; ++it) {                                    \
      *(bf16x8*)&Ks[kr + it * 16][kc] = kreg[it];                                         \
      *(bf16x8*)&Vs[vr + it * 32][vc] = vreg[it];                                         \
    }                                                                                     \
  }

  LOADTILE(klo);
  WRITETILE();
  __syncthreads();

  const int qg = q0 + wave * 16 + fr;

  for (int kt = klo; kt <= khi; ++kt) {
    const bool more = kt < khi;
    if (more) LOADTILE(kt + 1);

    f32x4 s[4];
    __builtin_amdgcn_s_setprio(1);
#pragma unroll
    for (int kk = 0; kk < 4; ++kk) {
      f32x4 a = (f32x4){0.f, 0.f, 0.f, 0.f};
#pragma unroll
      for (int ds = 0; ds < 4; ++ds) {
        bf16x8 kf = *(const bf16x8*)&Ks[kk * 16 + fr][ds * 32 + ko];
        a = MFMA16(kf, qf[ds], a);
      }
      s[kk] = a;
    }
    __builtin_amdgcn_s_setprio(0);

    float sv[16];
    float pmax = -1e30f;
#pragma unroll
    for (int kk = 0; kk < 4; ++kk)
#pragma unroll
      for (int reg = 0; reg < 4; ++reg) {
        const int cg = kt * KVB + kk * 16 + g4 + reg;
        const bool allowed = (cg <= qg) && (isglobal || cg >= qg - (WINDOW - 1));
        const float v = allowed ? s[kk][reg] : -1e30f;
        sv[kk * 4 + reg] = v;
        pmax = fmaxf(pmax, v);
      }
    pmax = fmaxf(pmax, __shfl_xor(pmax, 16, 64));
    pmax = fmaxf(pmax, __shfl_xor(pmax, 32, 64));
    const float nm = fmaxf(mrun, pmax);
    const float fac = __expf((mrun - nm) * SC);
    mrun = nm;
    float rs = 0.f;
    u16 pb[16];
#pragma unroll
    for (int i = 0; i < 16; ++i) {
      const float p = (sv[i] > -5e29f) ? __expf((sv[i] - nm) * SC) : 0.f;
      rs += p;
      pb[i] = f2bf(p);
    }
    rs += __shfl_xor(rs, 16, 64);
    rs += __shfl_xor(rs, 32, 64);
    lrun = lrun * fac + rs;

#pragma unroll
    for (int kk = 0; kk < 4; ++kk) {
      u16x4 w;
      w[0] = pb[kk * 4]; w[1] = pb[kk * 4 + 1]; w[2] = pb[kk * 4 + 2]; w[3] = pb[kk * 4 + 3];
      *(u16x4*)&Ps[wave][fr][kk * 16 + g4] = w;
    }

    float ff[4];
#pragma unroll
    for (int r = 0; r < 4; ++r) ff[r] = __shfl(fac, g4 + r, 64);
#pragma unroll
    for (int dt = 0; dt < 8; ++dt)
#pragma unroll
      for (int r = 0; r < 4; ++r) o[dt][r] *= ff[r];

    bf16x8 pf0 = *(const bf16x8*)&Ps[wave][fr][ko];
    bf16x8 pf1 = *(const bf16x8*)&Ps[wave][fr][32 + ko];
    __builtin_amdgcn_s_setprio(1);
#pragma unroll
    for (int dt = 0; dt < 8; ++dt) {
      bf16x8 vf0 = *(const bf16x8*)&Vs[dt * 16 + fr][ko];
      bf16x8 vf1 = *(const bf16x8*)&Vs[dt * 16 + fr][32 + ko];
      o[dt] = MFMA16(pf0, vf0, o[dt]);
      o[dt] = MFMA16(pf1, vf1, o[dt]);
    }
    __builtin_amdgcn_s_setprio(0);

    __syncthreads();
    if (more) WRITETILE();
    __syncthreads();
  }

  if (!partial) {
    const float inv = 1.0f / lrun;
    float iv[4];
#pragma unroll
    for (int r = 0; r < 4; ++r) iv[r] = __shfl(inv, g4 + r, 64);
#pragma unroll
    for (int r = 0; r < 4; ++r) {
      const int qrow = q0 + wave * 16 + g4 + r;
#pragma unroll
      for (int dt = 0; dt < 8; ++dt)
        op[baseo + (size_t)qrow * DMODEL + dt * 16 + fr] = f2bf(o[dt][r] * iv[r]);
    }
  } else {
    const int sidx = (((b * 8 + (h >> 1)) * 16 + (qt - 16)) << 1) + part;
    const size_t sb = (size_t)sidx * 64;
#pragma unroll
    for (int r = 0; r < 4; ++r) {
      const size_t row = sb + wave * 16 + g4 + r;
#pragma unroll
      for (int dt = 0; dt < 8; ++dt)
        pO[row * HDIM + dt * 16 + fr] = f2bf(o[dt][r]);
    }
    if (lane < 16) {
      pm[sb + wave * 16 + lane] = mrun;
      pl[sb + wave * 16 + lane] = lrun;
    }
  }
}

// ---------------------------------------------------------------------------
// Merge two partials per (b, even h, qt>=16). Grid 256 blocks x 256 thr.
// ---------------------------------------------------------------------------
__global__ __launch_bounds__(256) void merge_kernel(const u16* __restrict__ pO,
                                                    const float* __restrict__ pm,
                                                    const float* __restrict__ pl,
                                                    u16* __restrict__ op) {
  const int x = blockIdx.x;
  const int qt16 = x & 15, eh = (x >> 4) & 7, b = x >> 7;
  const int h = eh * 2, qt = 16 + qt16;
  const int s0 = x * 2, s1 = s0 + 1;

  for (int i = 0; i < 4; ++i) {
    const int vidx = threadIdx.x + i * 256;
    const int row = vidx >> 4, d8 = (vidx & 15) * 8;
    const float m0 = pm[s0 * 64 + row], m1 = pm[s1 * 64 + row];
    const float l0 = pl[s0 * 64 + row], l1 = pl[s1 * 64 + row];
    const float m = fmaxf(m0, m1);
    const float w0 = __expf((m0 - m) * SC), w1 = __expf((m1 - m) * SC);
    const float inv = 1.0f / (l0 * w0 + l1 * w1);
    bf16x8 a = *(const bf16x8*)&pO[((size_t)s0 * 64 + row) * HDIM + d8];
    bf16x8 c = *(const bf16x8*)&pO[((size_t)s1 * 64 + row) * HDIM + d8];
    bf16x8 r;
#pragma unroll
    for (int j = 0; j < 8; ++j)
      r[j] = (short)f2bf((bf2f((u16)a[j]) * w0 + bf2f((u16)c[j]) * w1) * inv);
    *(bf16x8*)&op[((size_t)(b * T_SEQ + qt * 64 + row)) * DMODEL + h * HDIM + d8] = r;
  }
}

// ---------------------------------------------------------------------------
extern "C" void kernel_launch(void* const* d_in, const int* in_sizes, int n_in,
                              void* d_out, int out_size, void* d_ws, size_t ws_size,
                              hipStream_t stream) {
  (void)in_sizes; (void)n_in; (void)out_size; (void)ws_size;
  const float* x  = (const float*)d_in[0];
  const float* Wq = (const float*)d_in[1];
  const float* Wk = (const float*)d_in[2];
  const float* Wv = (const float*)d_in[3];
  const float* Wo = (const float*)d_in[4];

  const size_t NX = (size_t)MROWS * DMODEL;
  const size_t NW = (size_t)DMODEL * DMODEL;
  u16* ws  = (u16*)d_ws;
  u16* xb  = ws;                 // bf16 x; later attention output
  u16* wqb = ws + NX;            // [wq|wk|wv] contiguous = Wcat[6144][2048]
  u16* wkb = wqb + NW;
  u16* wvb = wkb + NW;
  u16* wob = wvb + NW;
  u16* qkb = wob + NW;                          // [4096][4096]
  u16* vtb = qkb + (size_t)MROWS * 2 * DMODEL;  // [32][128][2048]

  u16*   pO = wqb;                               // partials reuse dead wq/wk region
  float* pm = (float*)(wqb + (size_t)512 * 64 * HDIM);
  float* pl = pm + 512 * 64;

  convert_all<<<2048, 256, 0, stream>>>(x, Wq, Wk, Wv, Wo, ws);

  gemm_qkv<<<384, 512, 0, stream>>>(xb, wqb, qkb, vtb);

  attn_kernel<<<dim3(48, NHEADS, 2), 256, 0, stream>>>(qkb, vtb, xb, pO, pm, pl);

  merge_kernel<<<256, 256, 0, stream>>>(pO, pm, pl, xb);

  gemm_out<<<dim3(DMODEL / BN, MROWS / BM), 256, 0, stream>>>(
      xb, wob, (float*)d_out, DMODEL);
}

// Round 7
// 276.841 us; speedup vs baseline: 1.0568x; 1.0568x over previous
//
#include <hip/hip_runtime.h>

typedef __attribute__((ext_vector_type(4))) float f32x4;
typedef __attribute__((ext_vector_type(8))) short bf16x8;
typedef __attribute__((ext_vector_type(4))) unsigned short u16x4;
typedef unsigned short u16;

#define MFMA16(a, b, c) __builtin_amdgcn_mfma_f32_16x16x32_bf16((a), (b), (c), 0, 0, 0)

#define T_SEQ 2048
#define DMODEL 2048
#define NHEADS 16
#define HDIM 128
#define WINDOW 256
#define MROWS 4096  // B*T
#define SC 0.08838834764831845f  // 1/sqrt(128)

__device__ __forceinline__ u16 f2bf(float f) {
  union { float f; unsigned u; } v; v.f = f;
  return (u16)((v.u + 0x7FFFu + ((v.u >> 16) & 1u)) >> 16);
}
__device__ __forceinline__ float bf2f(u16 u) {
  union { unsigned u; float f; } v; v.u = ((unsigned)u) << 16;
  return v.f;
}
__device__ __forceinline__ void gl_lds16(const u16* g, u16* l) {
  __builtin_amdgcn_global_load_lds((const __attribute__((address_space(1))) void*)(g),
                                   (__attribute__((address_space(3))) void*)(l), 16, 0, 0);
}

// ---------------------------------------------------------------------------
// Convert x, Wq, Wk, Wv, Wo (f32) -> contiguous bf16: [xb NX][wq][wk][wv][wo]
// ---------------------------------------------------------------------------
__global__ __launch_bounds__(256) void convert_all(const float* __restrict__ x,
                                                   const float* __restrict__ wq,
                                                   const float* __restrict__ wk,
                                                   const float* __restrict__ wv,
                                                   const float* __restrict__ wo,
                                                   u16* __restrict__ dst) {
  const size_t NX = (size_t)MROWS * DMODEL;
  const size_t NW = (size_t)DMODEL * DMODEL;
  const size_t chunks = (NX + 4 * NW) / 8;
  for (size_t ci = (size_t)blockIdx.x * 256 + threadIdx.x; ci < chunks;
       ci += (size_t)gridDim.x * 256) {
    const size_t off = ci * 8;
    const float* src;
    size_t so;
    if (off < NX) { src = x; so = off; }
    else {
      size_t rem = off - NX;
      if (rem < NW) { src = wq; so = rem; }
      else if (rem < 2 * NW) { src = wk; so = rem - NW; }
      else if (rem < 3 * NW) { src = wv; so = rem - 2 * NW; }
      else { src = wo; so = rem - 3 * NW; }
    }
    f32x4 a = *(const f32x4*)&src[so];
    f32x4 b = *(const f32x4*)&src[so + 4];
    bf16x8 o;
#pragma unroll
    for (int j = 0; j < 4; ++j) { o[j] = (short)f2bf(a[j]); o[j + 4] = (short)f2bf(b[j]); }
    *(bf16x8*)&dst[off] = o;
  }
}

// ---------------------------------------------------------------------------
// 8-phase QKV GEMM: C[4096,6144] = A @ Wcat^T, all bf16.
// BM=256, BN=192, BK=64. Grid 512 (16 mt x 32 nt) = EXACT 2 rounds @1blk/CU.
// 512 thr = 8 waves (2m x 4n), per-wave 128x48 (8mi x 3ni), 48 MFMA/K-tile.
// LDS 112 KB = 2 bufs x (A 32K + B 24K), XOR slot-swizzle (slot ^= row&7,
// 16B slots), pre-swizzled gl_lds source + swizzled ds_read (0-conflict).
// 7 gl_lds/thread/K-tile (A:4 = 2 halves x2, B:3 = Bh0 x2 + Bh1 x1).
// Ledger (iter i, t0=2i->buf0, t1=2i+1->buf1):
//  P1:Ah0(t1) P2:Ah1(t1) P3:Bh0(t0+2) P4:Bh1(t0+2)+VMC3  (forces t1; leaves 3)
//  P5:Ah0(t0+2) P6:Ah1(t0+2) P7:Bh0(t1+2) P8:Bh1(t1+2)+VMC3 (forces t0+2)
// Reads/phase: P1:AL(8) P2:B2(2) P3:AH(8) P4:B01-next(4, AFTER vmcnt).
// MFMA/phase: 16,8,16,8 under setprio. XCD map: xcd owns 4-nt W-slice (3 MB,
// L2-resident) x all 16 mt.
// ---------------------------------------------------------------------------
#define QKV_NT 32  // K-tiles (2048/64)

__global__ __launch_bounds__(512, 2) void gemm_qkv(const u16* __restrict__ A,
                                                   const u16* __restrict__ W,
                                                   u16* __restrict__ qk,
                                                   u16* __restrict__ vt) {
  __shared__ u16 lds[57344];  // 112 KB: A [0,32768), B [32768,57344)
  const int tid = threadIdx.x, w = tid >> 6, lane = tid & 63;
  const int wm = w >> 2, wn = w & 3;
  const int fr = lane & 15, g = lane >> 4, g4 = g * 4;

  // XCD map: 512 = 8 xcd x 64; xcd owns nt in [xcd*4, xcd*4+4) x all mt
  const int xcd = blockIdx.x & 7, bi = blockIdx.x >> 3;
  const int mt = bi >> 2, nt = xcd * 4 + (bi & 3);
  const int m0 = mt * 256, n0 = nt * 192;

  // frag-read swizzle: LDS slot = (kc*4+g) ^ (fr&7), 16B slots, row stride 64
  const int xs0 = (g ^ (fr & 7)) * 8;
  const int xs1 = xs0 ^ 32;
  const int aRow = wm * 128 + fr;
  const int bRow = wn * 48 + fr;

  // staging: thread covers (row sr, slot tid&7); source chunk inverse-swizzled
  const int sr = tid >> 3;                       // 0..63
  const int scc = ((tid & 7) ^ (sr & 7)) * 8;    // pre-swizzled source chunk
  const u16* pA0  = A + (size_t)(m0 + sr) * DMODEL + scc;
  const u16* pA1  = A + (size_t)(m0 + 64 + sr) * DMODEL + scc;
  const u16* pB0  = W + (size_t)(n0 + sr) * DMODEL + scc;
  const u16* pB0b = W + (size_t)(n0 + 64 + sr) * DMODEL + scc;
  const u16* pB1  = W + (size_t)(n0 + 128 + sr) * DMODEL + scc;

#define BAR __builtin_amdgcn_s_barrier()
#define FEN asm volatile("" ::: "memory")
#define VMC3 asm volatile("s_waitcnt vmcnt(3)" ::: "memory")
#define VMC0 asm volatile("s_waitcnt vmcnt(0)" ::: "memory")

#define SAH(h, t, c)                                                                   \
  { gl_lds16(pA0 + (size_t)(h) * 128 * DMODEL + (t) * 64,                              \
             &lds[(c) * 16384 + (h) * 8192 + w * 512]);                                \
    gl_lds16(pA1 + (size_t)(h) * 128 * DMODEL + (t) * 64,                              \
             &lds[(c) * 16384 + (h) * 8192 + 4096 + w * 512]); }
#define SBH0(t, c)                                                                     \
  { gl_lds16(pB0 + (size_t)(t) * 64, &lds[32768 + (c) * 12288 + w * 512]);             \
    gl_lds16(pB0b + (size_t)(t) * 64, &lds[32768 + (c) * 12288 + 4096 + w * 512]); }
#define SBH1(t, c)                                                                     \
  { gl_lds16(pB1 + (size_t)(t) * 64, &lds[32768 + (c) * 12288 + 8192 + w * 512]); }

#define RD_AL(c)                                                                       \
  { _Pragma("unroll") for (int m_ = 0; m_ < 4; ++m_) {                                 \
      af[m_][0] = *(const bf16x8*)&lds[(c) * 16384 + (aRow + m_ * 16) * 64 + xs0];     \
      af[m_][1] = *(const bf16x8*)&lds[(c) * 16384 + (aRow + m_ * 16) * 64 + xs1]; } }
#define RD_AH(c)                                                                       \
  { _Pragma("unroll") for (int m_ = 0; m_ < 4; ++m_) {                                 \
      af[m_][0] = *(const bf16x8*)&lds[(c) * 16384 + (aRow + 64 + m_ * 16) * 64 + xs0];\
      af[m_][1] = *(const bf16x8*)&lds[(c) * 16384 + (aRow + 64 + m_ * 16) * 64 + xs1]; } }
#define RD_B01(c)                                                                      \
  { _Pragma("unroll") for (int n_ = 0; n_ < 2; ++n_) {                                 \
      bfr[n_][0] = *(const bf16x8*)&lds[32768 + (c) * 12288 + (bRow + n_ * 16) * 64 + xs0]; \
      bfr[n_][1] = *(const bf16x8*)&lds[32768 + (c) * 12288 + (bRow + n_ * 16) * 64 + xs1]; } }
#define RD_B2(c)                                                                       \
  { bfr[2][0] = *(const bf16x8*)&lds[32768 + (c) * 12288 + (bRow + 32) * 64 + xs0];    \
    bfr[2][1] = *(const bf16x8*)&lds[32768 + (c) * 12288 + (bRow + 32) * 64 + xs1]; }

#define MMQA(MB)                                                                       \
  { __builtin_amdgcn_s_setprio(1);                                                    \
    _Pragma("unroll") for (int kc_ = 0; kc_ < 2; ++kc_)                                \
      _Pragma("unroll") for (int m_ = 0; m_ < 4; ++m_)                                 \
        _Pragma("unroll") for (int n_ = 0; n_ < 2; ++n_)                               \
          acc[(MB) + m_][n_] = MFMA16(af[m_][kc_], bfr[n_][kc_], acc[(MB) + m_][n_]);  \
    __builtin_amdgcn_s_setprio(0); }
#define MMQB(MB)                                                                       \
  { __builtin_amdgcn_s_setprio(1);                                                    \
    _Pragma("unroll") for (int kc_ = 0; kc_ < 2; ++kc_)                                \
      _Pragma("unroll") for (int m_ = 0; m_ < 4; ++m_)                                 \
        acc[(MB) + m_][2] = MFMA16(af[m_][kc_], bfr[2][kc_], acc[(MB) + m_][2]);       \
    __builtin_amdgcn_s_setprio(0); }

  bf16x8 af[4][2], bfr[3][2];
  f32x4 acc[8][3];
#pragma unroll
  for (int i = 0; i < 8; ++i)
#pragma unroll
    for (int j = 0; j < 3; ++j) acc[i][j] = (f32x4){0.f, 0.f, 0.f, 0.f};

  // prologue: A(0),B(0)->buf0 (7 loads); B(1)->buf1 (3); vmcnt(3) leaves B(1)
  SAH(0, 0, 0); SAH(1, 0, 0);
  SBH0(0, 0); SBH1(0, 0);
  SBH0(1, 1); SBH1(1, 1);
  VMC3; BAR;
  RD_B01(0);

  for (int i = 0; i < 15; ++i) {
    const int t0 = 2 * i;
    // P1 [buf0]
    RD_AL(0); SAH(0, t0 + 1, 1);
    FEN; BAR; MMQA(0); FEN; BAR;
    // P2
    RD_B2(0); SAH(1, t0 + 1, 1);
    FEN; BAR; MMQB(0); FEN; BAR;
    // P3
    RD_AH(0); SBH0(t0 + 2, 0);
    FEN; BAR; MMQA(4); FEN; BAR;
    // P4
    SBH1(t0 + 2, 0);
    VMC3; RD_B01(1);
    FEN; BAR; MMQB(4); FEN; BAR;
    // P5 [buf1]
    RD_AL(1); SAH(0, t0 + 2, 0);
    FEN; BAR; MMQA(0); FEN; BAR;
    // P6
    RD_B2(1); SAH(1, t0 + 2, 0);
    FEN; BAR; MMQB(0); FEN; BAR;
    // P7
    RD_AH(1); SBH0(t0 + 3, 1);
    FEN; BAR; MMQA(4); FEN; BAR;
    // P8
    SBH1(t0 + 3, 1);
    VMC3; RD_B01(0);
    FEN; BAR; MMQB(4); FEN; BAR;
  }
  // tail: tiles 30 (buf0), 31 (buf1); A(31) staged T1/T2; drain at T4
  RD_AL(0); SAH(0, 31, 1);
  FEN; BAR; MMQA(0); FEN; BAR;
  RD_B2(0); SAH(1, 31, 1);
  FEN; BAR; MMQB(0); FEN; BAR;
  RD_AH(0);
  FEN; BAR; MMQA(4); FEN; BAR;
  VMC0; RD_B01(1);
  FEN; BAR; MMQB(4); FEN; BAR;
  RD_AL(1);
  FEN; BAR; MMQA(0); FEN; BAR;
  RD_B2(1);
  FEN; BAR; MMQB(0); FEN; BAR;
  RD_AH(1);
  FEN; BAR; MMQA(4); FEN; BAR;
  MMQB(4);

  // epilogue: C row = base + g4 + reg, col = base + fr
#pragma unroll
  for (int mi = 0; mi < 8; ++mi)
#pragma unroll
    for (int ni = 0; ni < 3; ++ni) {
      const int row0 = m0 + wm * 128 + mi * 16 + g4;
      const int cg = n0 + wn * 48 + ni * 16 + fr;
      if (cg < 2 * DMODEL) {
#pragma unroll
        for (int r = 0; r < 4; ++r)
          qk[(size_t)(row0 + r) * (2 * DMODEL) + cg] = f2bf(acc[mi][ni][r]);
      } else {
        const int cc = cg - 2 * DMODEL;
        const int hh = cc >> 7, d = cc & 127;
        const int bb = row0 >> 11, tl = row0 & 2047;
        u16x4 w4;
#pragma unroll
        for (int r = 0; r < 4; ++r) w4[r] = f2bf(acc[mi][ni][r]);
        *(u16x4*)&vt[((size_t)(bb * NHEADS + hh) * HDIM + d) * T_SEQ + tl] = w4;
      }
    }
#undef SAH
#undef SBH0
#undef SBH1
}

// ---------------------------------------------------------------------------
// m97-structure GEMM (out-projection, unchanged known-good). C = A @ W^T, f32.
// ---------------------------------------------------------------------------
#define BM 128
#define BN 128
#define BK 32

__global__ __launch_bounds__(256) void gemm_out(const u16* __restrict__ A,
                                                const u16* __restrict__ W0,
                                                float* __restrict__ outf,
                                                int K) {
  __shared__ u16 As[BM * BK];
  __shared__ u16 Bs[BN * BK];
  const int tid = threadIdx.x, wave = tid >> 6, lane = tid & 63;
  const int fr = lane & 15, ko = (lane >> 4) * 8;
  const int wm = (wave >> 1) * 64, wn = (wave & 1) * 64;

  int flat = blockIdx.y * gridDim.x + blockIdx.x;
  const int nwg = gridDim.x * gridDim.y;
  const int cpx = nwg >> 3;
  flat = (flat & 7) * cpx + (flat >> 3);
  const int m0 = (flat / gridDim.x) * BM;
  const int n0 = (flat % gridDim.x) * BN;

  const int srow = tid >> 2;
  const int scol = (tid & 3) * 8;

  f32x4 acc[4][4];
#pragma unroll
  for (int i = 0; i < 4; ++i)
#pragma unroll
    for (int j = 0; j < 4; ++j) acc[i][j] = (f32x4){0.f, 0.f, 0.f, 0.f};

  for (int k0 = 0; k0 < K; k0 += BK) {
#pragma unroll
    for (int i = 0; i < 2; ++i) {
      const int row = srow + i * 64;
      gl_lds16(&A[(size_t)(m0 + row) * K + k0 + scol], &As[(i * 256 + wave * 64) * 8]);
      gl_lds16(&W0[(size_t)(n0 + row) * K + k0 + scol], &Bs[(i * 256 + wave * 64) * 8]);
    }
    __syncthreads();
    bf16x8 af[4], bfr[4];
#pragma unroll
    for (int i = 0; i < 4; ++i) af[i] = *(const bf16x8*)&As[(wm + i * 16 + fr) * BK + ko];
#pragma unroll
    for (int i = 0; i < 4; ++i) bfr[i] = *(const bf16x8*)&Bs[(wn + i * 16 + fr) * BK + ko];
#pragma unroll
    for (int mi = 0; mi < 4; ++mi)
#pragma unroll
      for (int ni = 0; ni < 4; ++ni)
        acc[mi][ni] = MFMA16(af[mi], bfr[ni], acc[mi][ni]);
    __syncthreads();
  }

#pragma unroll
  for (int mi = 0; mi < 4; ++mi)
#pragma unroll
    for (int ni = 0; ni < 4; ++ni) {
      const int row0 = m0 + wm + mi * 16 + (lane >> 4) * 4;
      const int c = n0 + wn + ni * 16 + fr;
#pragma unroll
      for (int r = 0; r < 4; ++r)
        outf[(size_t)(row0 + r) * DMODEL + c] = acc[mi][ni][r];
    }
}

// ---------------------------------------------------------------------------
// Striped flash attention (unchanged, known-good).
// ---------------------------------------------------------------------------
#define QB 64
#define KVB 64
#define LDK 136
#define LDV 72
#define LDP 80

__global__ __launch_bounds__(256) void attn_kernel(const u16* __restrict__ qk,
                                                   const u16* __restrict__ vt,
                                                   u16* __restrict__ op,
                                                   u16* __restrict__ pO,
                                                   float* __restrict__ pm,
                                                   float* __restrict__ pl) {
  __shared__ u16 Ks[KVB][LDK];
  __shared__ u16 Vs[HDIM][LDV];
  __shared__ u16 Ps[4][16][LDP];

  const int bx = blockIdx.x, h = blockIdx.y, b = blockIdx.z;
  const bool isglobal = (h & 1) == 0;
  int qt, klo, khi, part = 0;
  bool partial = false;
  if (isglobal) {
    const int c = 47 - bx;
    if (c < 16) { qt = c; klo = 0; khi = qt; }
    else {
      qt = 16 + ((c - 16) >> 1);
      part = (c - 16) & 1;
      partial = true;
      if (part == 0) { klo = 0; khi = 15; } else { klo = 16; khi = qt; }
    }
  } else {
    if (bx >= 32) return;
    qt = 31 - bx;
    const int lo_ = qt * QB - (WINDOW - 1);
    klo = lo_ > 0 ? (lo_ >> 6) : 0;
    khi = qt;
  }

  const int tid = threadIdx.x, wave = tid >> 6, lane = tid & 63;
  const int fr = lane & 15, ko = (lane >> 4) * 8, g4 = (lane >> 4) * 4;
  const int q0 = qt * QB;
  const size_t baseq = (size_t)b * T_SEQ * (2 * DMODEL) + (size_t)h * HDIM;
  const size_t basek = baseq + DMODEL;
  const size_t basev = (size_t)(b * NHEADS + h) * HDIM * T_SEQ;
  const size_t baseo = (size_t)b * T_SEQ * DMODEL + (size_t)h * HDIM;

  bf16x8 qf[4];
  {
    const int qrow = q0 + wave * 16 + fr;
#pragma unroll
    for (int ds = 0; ds < 4; ++ds)
      qf[ds] = *(const bf16x8*)&qk[baseq + (size_t)qrow * (2 * DMODEL) + ds * 32 + ko];
  }

  float mrun = -1e30f, lrun = 0.f;
  f32x4 o[8];
#pragma unroll
  for (int dt = 0; dt < 8; ++dt) o[dt] = (f32x4){0.f, 0.f, 0.f, 0.f};

  const int kr = tid >> 4, kc = (tid & 15) * 8;
  const int vr = tid >> 3, vc = (tid & 7) * 8;
  bf16x8 kreg[4], vreg[4];

#define LOADTILE(KT)                                                                      \
  {                                                                                       \
    _Pragma("unroll") for (int it = 0; it < 4; ++it) {                                    \
      kreg[it] = *(const bf16x8*)&qk[basek + (size_t)((KT) * KVB + kr + it * 16) * (2 * DMODEL) + kc]; \
      vreg[it] = *(const bf16x8*)&vt[basev + (size_t)(vr + it * 32) * T_SEQ + (KT) * KVB + vc];        \
    }                                                                                     \
  }
#define WRITETILE()                                                                       \
  {                                                                                       \
    _Pragma("unroll") for (int it = 0; it < 4; ++it) {                                    \
      *(bf16x8*)&Ks[kr + it * 16][kc] = kreg[it];                                         \
      *(bf16x8*)&Vs[vr + it * 32][vc] = vreg[it];                                         \
    }                                                                                     \
  }

  LOADTILE(klo);
  WRITETILE();
  __syncthreads();

  const int qg = q0 + wave * 16 + fr;

  for (int kt = klo; kt <= khi; ++kt) {
    const bool more = kt < khi;
    if (more) LOADTILE(kt + 1);

    f32x4 s[4];
    __builtin_amdgcn_s_setprio(1);
#pragma unroll
    for (int kk = 0; kk < 4; ++kk) {
      f32x4 a = (f32x4){0.f, 0.f, 0.f, 0.f};
#pragma unroll
      for (int ds = 0; ds < 4; ++ds) {
        bf16x8 kf = *(const bf16x8*)&Ks[kk * 16 + fr][ds * 32 + ko];
        a = MFMA16(kf, qf[ds], a);
      }
      s[kk] = a;
    }
    __builtin_amdgcn_s_setprio(0);

    float sv[16];
    float pmax = -1e30f;
#pragma unroll
    for (int kk = 0; kk < 4; ++kk)
#pragma unroll
      for (int reg = 0; reg < 4; ++reg) {
        const int cg = kt * KVB + kk * 16 + g4 + reg;
        const bool allowed = (cg <= qg) && (isglobal || cg >= qg - (WINDOW - 1));
        const float v = allowed ? s[kk][reg] : -1e30f;
        sv[kk * 4 + reg] = v;
        pmax = fmaxf(pmax, v);
      }
    pmax = fmaxf(pmax, __shfl_xor(pmax, 16, 64));
    pmax = fmaxf(pmax, __shfl_xor(pmax, 32, 64));
    const float nm = fmaxf(mrun, pmax);
    const float fac = __expf((mrun - nm) * SC);
    mrun = nm;
    float rs = 0.f;
    u16 pb[16];
#pragma unroll
    for (int i = 0; i < 16; ++i) {
      const float p = (sv[i] > -5e29f) ? __expf((sv[i] - nm) * SC) : 0.f;
      rs += p;
      pb[i] = f2bf(p);
    }
    rs += __shfl_xor(rs, 16, 64);
    rs += __shfl_xor(rs, 32, 64);
    lrun = lrun * fac + rs;

#pragma unroll
    for (int kk = 0; kk < 4; ++kk) {
      u16x4 w;
      w[0] = pb[kk * 4]; w[1] = pb[kk * 4 + 1]; w[2] = pb[kk * 4 + 2]; w[3] = pb[kk * 4 + 3];
      *(u16x4*)&Ps[wave][fr][kk * 16 + g4] = w;
    }

    float ff[4];
#pragma unroll
    for (int r = 0; r < 4; ++r) ff[r] = __shfl(fac, g4 + r, 64);
#pragma unroll
    for (int dt = 0; dt < 8; ++dt)
#pragma unroll
      for (int r = 0; r < 4; ++r) o[dt][r] *= ff[r];

    bf16x8 pf0 = *(const bf16x8*)&Ps[wave][fr][ko];
    bf16x8 pf1 = *(const bf16x8*)&Ps[wave][fr][32 + ko];
    __builtin_amdgcn_s_setprio(1);
#pragma unroll
    for (int dt = 0; dt < 8; ++dt) {
      bf16x8 vf0 = *(const bf16x8*)&Vs[dt * 16 + fr][ko];
      bf16x8 vf1 = *(const bf16x8*)&Vs[dt * 16 + fr][32 + ko];
      o[dt] = MFMA16(pf0, vf0, o[dt]);
      o[dt] = MFMA16(pf1, vf1, o[dt]);
    }
    __builtin_amdgcn_s_setprio(0);

    __syncthreads();
    if (more) WRITETILE();
    __syncthreads();
  }

  if (!partial) {
    const float inv = 1.0f / lrun;
    float iv[4];
#pragma unroll
    for (int r = 0; r < 4; ++r) iv[r] = __shfl(inv, g4 + r, 64);
#pragma unroll
    for (int r = 0; r < 4; ++r) {
      const int qrow = q0 + wave * 16 + g4 + r;
#pragma unroll
      for (int dt = 0; dt < 8; ++dt)
        op[baseo + (size_t)qrow * DMODEL + dt * 16 + fr] = f2bf(o[dt][r] * iv[r]);
    }
  } else {
    const int sidx = (((b * 8 + (h >> 1)) * 16 + (qt - 16)) << 1) + part;
    const size_t sb = (size_t)sidx * 64;
#pragma unroll
    for (int r = 0; r < 4; ++r) {
      const size_t row = sb + wave * 16 + g4 + r;
#pragma unroll
      for (int dt = 0; dt < 8; ++dt)
        pO[row * HDIM + dt * 16 + fr] = f2bf(o[dt][r]);
    }
    if (lane < 16) {
      pm[sb + wave * 16 + lane] = mrun;
      pl[sb + wave * 16 + lane] = lrun;
    }
  }
}

// ---------------------------------------------------------------------------
// Merge two partials per (b, even h, qt>=16). Grid 256 blocks x 256 thr.
// ---------------------------------------------------------------------------
__global__ __launch_bounds__(256) void merge_kernel(const u16* __restrict__ pO,
                                                    const float* __restrict__ pm,
                                                    const float* __restrict__ pl,
                                                    u16* __restrict__ op) {
  const int x = blockIdx.x;
  const int qt16 = x & 15, eh = (x >> 4) & 7, b = x >> 7;
  const int h = eh * 2, qt = 16 + qt16;
  const int s0 = x * 2, s1 = s0 + 1;

  for (int i = 0; i < 4; ++i) {
    const int vidx = threadIdx.x + i * 256;
    const int row = vidx >> 4, d8 = (vidx & 15) * 8;
    const float m0 = pm[s0 * 64 + row], m1 = pm[s1 * 64 + row];
    const float l0 = pl[s0 * 64 + row], l1 = pl[s1 * 64 + row];
    const float m = fmaxf(m0, m1);
    const float w0 = __expf((m0 - m) * SC), w1 = __expf((m1 - m) * SC);
    const float inv = 1.0f / (l0 * w0 + l1 * w1);
    bf16x8 a = *(const bf16x8*)&pO[((size_t)s0 * 64 + row) * HDIM + d8];
    bf16x8 c = *(const bf16x8*)&pO[((size_t)s1 * 64 + row) * HDIM + d8];
    bf16x8 r;
#pragma unroll
    for (int j = 0; j < 8; ++j)
      r[j] = (short)f2bf((bf2f((u16)a[j]) * w0 + bf2f((u16)c[j]) * w1) * inv);
    *(bf16x8*)&op[((size_t)(b * T_SEQ + qt * 64 + row)) * DMODEL + h * HDIM + d8] = r;
  }
}

// ---------------------------------------------------------------------------
extern "C" void kernel_launch(void* const* d_in, const int* in_sizes, int n_in,
                              void* d_out, int out_size, void* d_ws, size_t ws_size,
                              hipStream_t stream) {
  (void)in_sizes; (void)n_in; (void)out_size; (void)ws_size;
  const float* x  = (const float*)d_in[0];
  const float* Wq = (const float*)d_in[1];
  const float* Wk = (const float*)d_in[2];
  const float* Wv = (const float*)d_in[3];
  const float* Wo = (const float*)d_in[4];

  const size_t NX = (size_t)MROWS * DMODEL;
  const size_t NW = (size_t)DMODEL * DMODEL;
  u16* ws  = (u16*)d_ws;
  u16* xb  = ws;                 // bf16 x; later attention output
  u16* wqb = ws + NX;            // [wq|wk|wv] contiguous = Wcat[6144][2048]
  u16* wkb = wqb + NW;
  u16* wvb = wkb + NW;
  u16* wob = wvb + NW;
  u16* qkb = wob + NW;                          // [4096][4096]
  u16* vtb = qkb + (size_t)MROWS * 2 * DMODEL;  // [32][128][2048]

  u16*   pO = wqb;                               // partials reuse dead wq/wk region
  float* pm = (float*)(wqb + (size_t)512 * 64 * HDIM);
  float* pl = pm + 512 * 64;

  convert_all<<<2048, 256, 0, stream>>>(x, Wq, Wk, Wv, Wo, ws);

  gemm_qkv<<<512, 512, 0, stream>>>(xb, wqb, qkb, vtb);

  attn_kernel<<<dim3(48, NHEADS, 2), 256, 0, stream>>>(qkb, vtb, xb, pO, pm, pl);

  merge_kernel<<<256, 256, 0, stream>>>(pO, pm, pl, xb);

  gemm_out<<<dim3(DMODEL / BN, MROWS / BM), 256, 0, stream>>>(
      xb, wob, (float*)d_out, DMODEL);
}

// Round 8
// 256.854 us; speedup vs baseline: 1.1391x; 1.0778x over previous
//
#include <hip/hip_runtime.h>

typedef __attribute__((ext_vector_type(4))) float f32x4;
typedef __attribute__((ext_vector_type(8))) short bf16x8;
typedef __attribute__((ext_vector_type(4))) unsigned short u16x4;
typedef unsigned short u16;

#define MFMA16(a, b, c) __builtin_amdgcn_mfma_f32_16x16x32_bf16((a), (b), (c), 0, 0, 0)

#define T_SEQ 2048
#define DMODEL 2048
#define NHEADS 16
#define HDIM 128
#define WINDOW 256
#define MROWS 4096  // B*T
#define SC 0.08838834764831845f  // 1/sqrt(128)

__device__ __forceinline__ u16 f2bf(float f) {
  union { float f; unsigned u; } v; v.f = f;
  return (u16)((v.u + 0x7FFFu + ((v.u >> 16) & 1u)) >> 16);
}
__device__ __forceinline__ float bf2f(u16 u) {
  union { unsigned u; float f; } v; v.u = ((unsigned)u) << 16;
  return v.f;
}
__device__ __forceinline__ void gl_lds16(const u16* g, u16* l) {
  __builtin_amdgcn_global_load_lds((const __attribute__((address_space(1))) void*)(g),
                                   (__attribute__((address_space(3))) void*)(l), 16, 0, 0);
}

#define BAR __builtin_amdgcn_s_barrier()
#define FEN asm volatile("" ::: "memory")
#define VMC3 asm volatile("s_waitcnt vmcnt(3)" ::: "memory")
#define VMC2 asm volatile("s_waitcnt vmcnt(2)" ::: "memory")
#define VMC0 asm volatile("s_waitcnt vmcnt(0)" ::: "memory")

// ---------------------------------------------------------------------------
// Convert x, Wq, Wk, Wv, Wo (f32) -> contiguous bf16: [xb NX][wq][wk][wv][wo]
// ---------------------------------------------------------------------------
__global__ __launch_bounds__(256) void convert_all(const float* __restrict__ x,
                                                   const float* __restrict__ wq,
                                                   const float* __restrict__ wk,
                                                   const float* __restrict__ wv,
                                                   const float* __restrict__ wo,
                                                   u16* __restrict__ dst) {
  const size_t NX = (size_t)MROWS * DMODEL;
  const size_t NW = (size_t)DMODEL * DMODEL;
  const size_t chunks = (NX + 4 * NW) / 8;
  for (size_t ci = (size_t)blockIdx.x * 256 + threadIdx.x; ci < chunks;
       ci += (size_t)gridDim.x * 256) {
    const size_t off = ci * 8;
    const float* src;
    size_t so;
    if (off < NX) { src = x; so = off; }
    else {
      size_t rem = off - NX;
      if (rem < NW) { src = wq; so = rem; }
      else if (rem < 2 * NW) { src = wk; so = rem - NW; }
      else if (rem < 3 * NW) { src = wv; so = rem - 2 * NW; }
      else { src = wo; so = rem - 3 * NW; }
    }
    f32x4 a = *(const f32x4*)&src[so];
    f32x4 b = *(const f32x4*)&src[so + 4];
    bf16x8 o;
#pragma unroll
    for (int j = 0; j < 4; ++j) { o[j] = (short)f2bf(a[j]); o[j + 4] = (short)f2bf(b[j]); }
    *(bf16x8*)&dst[off] = o;
  }
}

// ---------------------------------------------------------------------------
// 2-phase QKV GEMM: C[4096,6144] = A @ Wcat^T, all bf16.
// BM=256, BN=192, BK=64. Grid 512 (16 mt x 32 nt) = exact 2 rounds @1blk/CU.
// 512 thr = 8 waves (2m x 4n), per-wave 128x48; 2 phases x 24 MFMA per K-tile.
// LDS 112 KB dbuf, XOR slot-swizzle (slot ^= row&7, 16B slots), 0-conflict.
// 7 gl_lds/thr/K-tile. Ledger (tile t, buf c=t&1):
//  Ph1: rd AL+B (14 b128) | stage A(t+1)->c^1 [4] | BAR | 24 MFMA | BAR
//  Ph2: rd AH (8)         | stage B(t+2)->c   [3] | VMC3 | BAR | 24 MFMA | BAR
// VMC3 @Ph2 forces B(t+1)+A(t+1), leaves B(t+2) in flight. Tail t=30: VMC0.
// ---------------------------------------------------------------------------
__global__ __launch_bounds__(512, 2) void gemm_qkv(const u16* __restrict__ A,
                                                   const u16* __restrict__ W,
                                                   u16* __restrict__ qk,
                                                   u16* __restrict__ vt) {
  __shared__ u16 lds[57344];  // A: [0,32768) x2 bufs; B: [32768,57344) x2 bufs
  const int tid = threadIdx.x, w = tid >> 6, lane = tid & 63;
  const int wm = w >> 2, wn = w & 3;
  const int fr = lane & 15, g = lane >> 4, g4 = g * 4;

  // XCD map: xcd owns 4-nt W-slice (3 MB, L2-resident) x all 16 mt
  const int xcd = blockIdx.x & 7, bi = blockIdx.x >> 3;
  const int mt = bi >> 2, nt = xcd * 4 + (bi & 3);
  const int m0 = mt * 256, n0 = nt * 192;

  const int xs0 = (g ^ (fr & 7)) * 8;
  const int xs1 = xs0 ^ 32;
  const int aRow = wm * 128 + fr;
  const int bRow = wn * 48 + fr;

  const int sr = tid >> 3;
  const int scc = ((tid & 7) ^ (sr & 7)) * 8;
  const u16* pA0  = A + (size_t)(m0 + sr) * DMODEL + scc;
  const u16* pA1  = A + (size_t)(m0 + 64 + sr) * DMODEL + scc;
  const u16* pB0  = W + (size_t)(n0 + sr) * DMODEL + scc;
  const u16* pB0b = W + (size_t)(n0 + 64 + sr) * DMODEL + scc;
  const u16* pB1  = W + (size_t)(n0 + 128 + sr) * DMODEL + scc;

#define SAH(h, t, c)                                                                   \
  { gl_lds16(pA0 + (size_t)(h) * 128 * DMODEL + (t) * 64,                              \
             &lds[(c) * 16384 + (h) * 8192 + w * 512]);                                \
    gl_lds16(pA1 + (size_t)(h) * 128 * DMODEL + (t) * 64,                              \
             &lds[(c) * 16384 + (h) * 8192 + 4096 + w * 512]); }
#define SBH0(t, c)                                                                     \
  { gl_lds16(pB0 + (size_t)(t) * 64, &lds[32768 + (c) * 12288 + w * 512]);             \
    gl_lds16(pB0b + (size_t)(t) * 64, &lds[32768 + (c) * 12288 + 4096 + w * 512]); }
#define SBH1(t, c)                                                                     \
  { gl_lds16(pB1 + (size_t)(t) * 64, &lds[32768 + (c) * 12288 + 8192 + w * 512]); }

#define RD_AL(c)                                                                       \
  { _Pragma("unroll") for (int m_ = 0; m_ < 4; ++m_) {                                 \
      af[m_][0] = *(const bf16x8*)&lds[(c) * 16384 + (aRow + m_ * 16) * 64 + xs0];     \
      af[m_][1] = *(const bf16x8*)&lds[(c) * 16384 + (aRow + m_ * 16) * 64 + xs1]; } }
#define RD_AH(c)                                                                       \
  { _Pragma("unroll") for (int m_ = 0; m_ < 4; ++m_) {                                 \
      af[m_][0] = *(const bf16x8*)&lds[(c) * 16384 + (aRow + 64 + m_ * 16) * 64 + xs0];\
      af[m_][1] = *(const bf16x8*)&lds[(c) * 16384 + (aRow + 64 + m_ * 16) * 64 + xs1]; } }
#define RD_B(c)                                                                        \
  { _Pragma("unroll") for (int n_ = 0; n_ < 3; ++n_) {                                 \
      bfr[n_][0] = *(const bf16x8*)&lds[32768 + (c) * 12288 + (bRow + n_ * 16) * 64 + xs0]; \
      bfr[n_][1] = *(const bf16x8*)&lds[32768 + (c) * 12288 + (bRow + n_ * 16) * 64 + xs1]; } }

#define MMQ(MB)                                                                        \
  { __builtin_amdgcn_s_setprio(1);                                                    \
    _Pragma("unroll") for (int kc_ = 0; kc_ < 2; ++kc_)                                \
      _Pragma("unroll") for (int m_ = 0; m_ < 4; ++m_)                                 \
        _Pragma("unroll") for (int n_ = 0; n_ < 3; ++n_)                               \
          acc[(MB) + m_][n_] = MFMA16(af[m_][kc_], bfr[n_][kc_], acc[(MB) + m_][n_]);  \
    __builtin_amdgcn_s_setprio(0); }

  bf16x8 af[4][2], bfr[3][2];
  f32x4 acc[8][3];
#pragma unroll
  for (int i = 0; i < 8; ++i)
#pragma unroll
    for (int j = 0; j < 3; ++j) acc[i][j] = (f32x4){0.f, 0.f, 0.f, 0.f};

  // prologue: A(0),B(0)->buf0; B(1)->buf1; VMC3 forces tile0, leaves B(1)
  SAH(0, 0, 0); SAH(1, 0, 0);
  SBH0(0, 0); SBH1(0, 0);
  SBH0(1, 1); SBH1(1, 1);
  VMC3; BAR;

#pragma unroll 1
  for (int i = 0; i < 15; ++i) {
    const int t0 = 2 * i;
    // tile t0 (buf0)
    RD_AL(0); RD_B(0); SAH(0, t0 + 1, 1); SAH(1, t0 + 1, 1);
    FEN; BAR; MMQ(0); FEN; BAR;
    RD_AH(0); SBH0(t0 + 2, 0); SBH1(t0 + 2, 0);
    VMC3; BAR; MMQ(4); FEN; BAR;
    // tile t0+1 (buf1)
    RD_AL(1); RD_B(1); SAH(0, t0 + 2, 0); SAH(1, t0 + 2, 0);
    FEN; BAR; MMQ(0); FEN; BAR;
    RD_AH(1); SBH0(t0 + 3, 1); SBH1(t0 + 3, 1);
    VMC3; BAR; MMQ(4); FEN; BAR;
  }
  // tail: t=30 (buf0), t=31 (buf1)
  RD_AL(0); RD_B(0); SAH(0, 31, 1); SAH(1, 31, 1);
  FEN; BAR; MMQ(0); FEN; BAR;
  RD_AH(0);
  VMC0; BAR; MMQ(4); FEN; BAR;
  RD_AL(1); RD_B(1);
  FEN; BAR; MMQ(0); FEN; BAR;
  RD_AH(1);
  FEN; BAR; MMQ(4);

  // epilogue: C row = base + g4 + reg, col = base + fr
#pragma unroll
  for (int mi = 0; mi < 8; ++mi)
#pragma unroll
    for (int ni = 0; ni < 3; ++ni) {
      const int row0 = m0 + wm * 128 + mi * 16 + g4;
      const int cg = n0 + wn * 48 + ni * 16 + fr;
      if (cg < 2 * DMODEL) {
#pragma unroll
        for (int r = 0; r < 4; ++r)
          qk[(size_t)(row0 + r) * (2 * DMODEL) + cg] = f2bf(acc[mi][ni][r]);
      } else {
        const int cc = cg - 2 * DMODEL;
        const int hh = cc >> 7, d = cc & 127;
        const int bb = row0 >> 11, tl = row0 & 2047;
        u16x4 w4;
#pragma unroll
        for (int r = 0; r < 4; ++r) w4[r] = f2bf(acc[mi][ni][r]);
        *(u16x4*)&vt[((size_t)(bb * NHEADS + hh) * HDIM + d) * T_SEQ + tl] = w4;
      }
    }
#undef SAH
#undef SBH0
#undef SBH1
#undef RD_AL
#undef RD_AH
#undef RD_B
#undef MMQ
}

// ---------------------------------------------------------------------------
// 2-phase out-proj GEMM: out[4096,2048] = A(bf16) @ Wo^T(bf16), f32 out.
// BM=256, BN=128, BK=64. Grid 256 (16 mt x 16 nt) = exact 1 round @1blk/CU.
// 8 waves (2m x 4n), per-wave 128x32; 2 phases x 16 MFMA per K-tile.
// LDS 96 KB dbuf, same swizzle. 6 gl_lds/thr/K-tile; VMC2 ledger.
// ---------------------------------------------------------------------------
__global__ __launch_bounds__(512, 2) void gemm_out(const u16* __restrict__ A,
                                                   const u16* __restrict__ W0,
                                                   float* __restrict__ outf) {
  __shared__ u16 lds2[49152];  // A: [0,32768) x2; B: [32768,49152) x2
  const int tid = threadIdx.x, w = tid >> 6, lane = tid & 63;
  const int wm = w >> 2, wn = w & 3;
  const int fr = lane & 15, g = lane >> 4, g4 = g * 4;

  // XCD map: xcd owns 2-nt Wo-slice (1 MB, L2-resident) x all 16 mt
  const int xcd = blockIdx.x & 7, bi = blockIdx.x >> 3;
  const int mt = bi >> 1, nt = xcd * 2 + (bi & 1);
  const int m0 = mt * 256, n0 = nt * 128;

  const int xs0 = (g ^ (fr & 7)) * 8;
  const int xs1 = xs0 ^ 32;
  const int aRow = wm * 128 + fr;
  const int bRow = wn * 32 + fr;

  const int sr = tid >> 3;
  const int scc = ((tid & 7) ^ (sr & 7)) * 8;
  const u16* pA0  = A + (size_t)(m0 + sr) * DMODEL + scc;
  const u16* pA1  = A + (size_t)(m0 + 64 + sr) * DMODEL + scc;
  const u16* pB0  = W0 + (size_t)(n0 + sr) * DMODEL + scc;
  const u16* pB0b = W0 + (size_t)(n0 + 64 + sr) * DMODEL + scc;

#define S2A(h, t, c)                                                                   \
  { gl_lds16(pA0 + (size_t)(h) * 128 * DMODEL + (t) * 64,                              \
             &lds2[(c) * 16384 + (h) * 8192 + w * 512]);                               \
    gl_lds16(pA1 + (size_t)(h) * 128 * DMODEL + (t) * 64,                              \
             &lds2[(c) * 16384 + (h) * 8192 + 4096 + w * 512]); }
#define S2B(t, c)                                                                      \
  { gl_lds16(pB0 + (size_t)(t) * 64, &lds2[32768 + (c) * 8192 + w * 512]);             \
    gl_lds16(pB0b + (size_t)(t) * 64, &lds2[32768 + (c) * 8192 + 4096 + w * 512]); }

#define R2AL(c)                                                                        \
  { _Pragma("unroll") for (int m_ = 0; m_ < 4; ++m_) {                                 \
      af[m_][0] = *(const bf16x8*)&lds2[(c) * 16384 + (aRow + m_ * 16) * 64 + xs0];    \
      af[m_][1] = *(const bf16x8*)&lds2[(c) * 16384 + (aRow + m_ * 16) * 64 + xs1]; } }
#define R2AH(c)                                                                        \
  { _Pragma("unroll") for (int m_ = 0; m_ < 4; ++m_) {                                 \
      af[m_][0] = *(const bf16x8*)&lds2[(c) * 16384 + (aRow + 64 + m_ * 16) * 64 + xs0]; \
      af[m_][1] = *(const bf16x8*)&lds2[(c) * 16384 + (aRow + 64 + m_ * 16) * 64 + xs1]; } }
#define R2B(c)                                                                         \
  { _Pragma("unroll") for (int n_ = 0; n_ < 2; ++n_) {                                 \
      bfr[n_][0] = *(const bf16x8*)&lds2[32768 + (c) * 8192 + (bRow + n_ * 16) * 64 + xs0]; \
      bfr[n_][1] = *(const bf16x8*)&lds2[32768 + (c) * 8192 + (bRow + n_ * 16) * 64 + xs1]; } }

#define M2(MB)                                                                         \
  { __builtin_amdgcn_s_setprio(1);                                                    \
    _Pragma("unroll") for (int kc_ = 0; kc_ < 2; ++kc_)                                \
      _Pragma("unroll") for (int m_ = 0; m_ < 4; ++m_)                                 \
        _Pragma("unroll") for (int n_ = 0; n_ < 2; ++n_)                               \
          acc[(MB) + m_][n_] = MFMA16(af[m_][kc_], bfr[n_][kc_], acc[(MB) + m_][n_]);  \
    __builtin_amdgcn_s_setprio(0); }

  bf16x8 af[4][2], bfr[2][2];
  f32x4 acc[8][2];
#pragma unroll
  for (int i = 0; i < 8; ++i)
#pragma unroll
    for (int j = 0; j < 2; ++j) acc[i][j] = (f32x4){0.f, 0.f, 0.f, 0.f};

  // prologue: A(0),B(0)->buf0; B(1)->buf1; VMC2 forces tile0, leaves B(1)
  S2A(0, 0, 0); S2A(1, 0, 0);
  S2B(0, 0);
  S2B(1, 1);
  VMC2; BAR;

#pragma unroll 1
  for (int i = 0; i < 15; ++i) {
    const int t0 = 2 * i;
    // tile t0 (buf0)
    R2AL(0); R2B(0); S2A(0, t0 + 1, 1); S2A(1, t0 + 1, 1);
    FEN; BAR; M2(0); FEN; BAR;
    R2AH(0); S2B(t0 + 2, 0);
    VMC2; BAR; M2(4); FEN; BAR;
    // tile t0+1 (buf1)
    R2AL(1); R2B(1); S2A(0, t0 + 2, 0); S2A(1, t0 + 2, 0);
    FEN; BAR; M2(0); FEN; BAR;
    R2AH(1); S2B(t0 + 3, 1);
    VMC2; BAR; M2(4); FEN; BAR;
  }
  // tail: t=30 (buf0), t=31 (buf1)
  R2AL(0); R2B(0); S2A(0, 31, 1); S2A(1, 31, 1);
  FEN; BAR; M2(0); FEN; BAR;
  R2AH(0);
  VMC0; BAR; M2(4); FEN; BAR;
  R2AL(1); R2B(1);
  FEN; BAR; M2(0); FEN; BAR;
  R2AH(1);
  FEN; BAR; M2(4);

  // epilogue: f32 stores, 16 lanes x 4B = 64B contiguous per row-quad
#pragma unroll
  for (int mi = 0; mi < 8; ++mi)
#pragma unroll
    for (int ni = 0; ni < 2; ++ni) {
      const int row0 = m0 + wm * 128 + mi * 16 + g4;
      const int c = n0 + wn * 32 + ni * 16 + fr;
#pragma unroll
      for (int r = 0; r < 4; ++r)
        outf[(size_t)(row0 + r) * DMODEL + c] = acc[mi][ni][r];
    }
#undef S2A
#undef S2B
#undef R2AL
#undef R2AH
#undef R2B
#undef M2
}

// ---------------------------------------------------------------------------
// Striped flash attention (unchanged, known-good).
// ---------------------------------------------------------------------------
#define QB 64
#define KVB 64
#define LDK 136
#define LDV 72
#define LDP 80

__global__ __launch_bounds__(256) void attn_kernel(const u16* __restrict__ qk,
                                                   const u16* __restrict__ vt,
                                                   u16* __restrict__ op,
                                                   u16* __restrict__ pO,
                                                   float* __restrict__ pm,
                                                   float* __restrict__ pl) {
  __shared__ u16 Ks[KVB][LDK];
  __shared__ u16 Vs[HDIM][LDV];
  __shared__ u16 Ps[4][16][LDP];

  const int bx = blockIdx.x, h = blockIdx.y, b = blockIdx.z;
  const bool isglobal = (h & 1) == 0;
  int qt, klo, khi, part = 0;
  bool partial = false;
  if (isglobal) {
    const int c = 47 - bx;
    if (c < 16) { qt = c; klo = 0; khi = qt; }
    else {
      qt = 16 + ((c - 16) >> 1);
      part = (c - 16) & 1;
      partial = true;
      if (part == 0) { klo = 0; khi = 15; } else { klo = 16; khi = qt; }
    }
  } else {
    if (bx >= 32) return;
    qt = 31 - bx;
    const int lo_ = qt * QB - (WINDOW - 1);
    klo = lo_ > 0 ? (lo_ >> 6) : 0;
    khi = qt;
  }

  const int tid = threadIdx.x, wave = tid >> 6, lane = tid & 63;
  const int fr = lane & 15, ko = (lane >> 4) * 8, g4 = (lane >> 4) * 4;
  const int q0 = qt * QB;
  const size_t baseq = (size_t)b * T_SEQ * (2 * DMODEL) + (size_t)h * HDIM;
  const size_t basek = baseq + DMODEL;
  const size_t basev = (size_t)(b * NHEADS + h) * HDIM * T_SEQ;
  const size_t baseo = (size_t)b * T_SEQ * DMODEL + (size_t)h * HDIM;

  bf16x8 qf[4];
  {
    const int qrow = q0 + wave * 16 + fr;
#pragma unroll
    for (int ds = 0; ds < 4; ++ds)
      qf[ds] = *(const bf16x8*)&qk[baseq + (size_t)qrow * (2 * DMODEL) + ds * 32 + ko];
  }

  float mrun = -1e30f, lrun = 0.f;
  f32x4 o[8];
#pragma unroll
  for (int dt = 0; dt < 8; ++dt) o[dt] = (f32x4){0.f, 0.f, 0.f, 0.f};

  const int kr = tid >> 4, kc = (tid & 15) * 8;
  const int vr = tid >> 3, vc = (tid & 7) * 8;
  bf16x8 kreg[4], vreg[4];

#define LOADTILE(KT)                                                                      \
  {                                                                                       \
    _Pragma("unroll") for (int it = 0; it < 4; ++it) {                                    \
      kreg[it] = *(const bf16x8*)&qk[basek + (size_t)((KT) * KVB + kr + it * 16) * (2 * DMODEL) + kc]; \
      vreg[it] = *(const bf16x8*)&vt[basev + (size_t)(vr + it * 32) * T_SEQ + (KT) * KVB + vc];        \
    }                                                                                     \
  }
#define WRITETILE()                                                                       \
  {                                                                                       \
    _Pragma("unroll") for (int it = 0; it < 4; ++it) {                                    \
      *(bf16x8*)&Ks[kr + it * 16][kc] = kreg[it];                                         \
      *(bf16x8*)&Vs[vr + it * 32][vc] = vreg[it];                                         \
    }                                                                                     \
  }

  LOADTILE(klo);
  WRITETILE();
  __syncthreads();

  const int qg = q0 + wave * 16 + fr;

  for (int kt = klo; kt <= khi; ++kt) {
    const bool more = kt < khi;
    if (more) LOADTILE(kt + 1);

    f32x4 s[4];
    __builtin_amdgcn_s_setprio(1);
#pragma unroll
    for (int kk = 0; kk < 4; ++kk) {
      f32x4 a = (f32x4){0.f, 0.f, 0.f, 0.f};
#pragma unroll
      for (int ds = 0; ds < 4; ++ds) {
        bf16x8 kf = *(const bf16x8*)&Ks[kk * 16 + fr][ds * 32 + ko];
        a = MFMA16(kf, qf[ds], a);
      }
      s[kk] = a;
    }
    __builtin_amdgcn_s_setprio(0);

    float sv[16];
    float pmax = -1e30f;
#pragma unroll
    for (int kk = 0; kk < 4; ++kk)
#pragma unroll
      for (int reg = 0; reg < 4; ++reg) {
        const int cg = kt * KVB + kk * 16 + g4 + reg;
        const bool allowed = (cg <= qg) && (isglobal || cg >= qg - (WINDOW - 1));
        const float v = allowed ? s[kk][reg] : -1e30f;
        sv[kk * 4 + reg] = v;
        pmax = fmaxf(pmax, v);
      }
    pmax = fmaxf(pmax, __shfl_xor(pmax, 16, 64));
    pmax = fmaxf(pmax, __shfl_xor(pmax, 32, 64));
    const float nm = fmaxf(mrun, pmax);
    const float fac = __expf((mrun - nm) * SC);
    mrun = nm;
    float rs = 0.f;
    u16 pb[16];
#pragma unroll
    for (int i = 0; i < 16; ++i) {
      const float p = (sv[i] > -5e29f) ? __expf((sv[i] - nm) * SC) : 0.f;
      rs += p;
      pb[i] = f2bf(p);
    }
    rs += __shfl_xor(rs, 16, 64);
    rs += __shfl_xor(rs, 32, 64);
    lrun = lrun * fac + rs;

#pragma unroll
    for (int kk = 0; kk < 4; ++kk) {
      u16x4 w;
      w[0] = pb[kk * 4]; w[1] = pb[kk * 4 + 1]; w[2] = pb[kk * 4 + 2]; w[3] = pb[kk * 4 + 3];
      *(u16x4*)&Ps[wave][fr][kk * 16 + g4] = w;
    }

    float ff[4];
#pragma unroll
    for (int r = 0; r < 4; ++r) ff[r] = __shfl(fac, g4 + r, 64);
#pragma unroll
    for (int dt = 0; dt < 8; ++dt)
#pragma unroll
      for (int r = 0; r < 4; ++r) o[dt][r] *= ff[r];

    bf16x8 pf0 = *(const bf16x8*)&Ps[wave][fr][ko];
    bf16x8 pf1 = *(const bf16x8*)&Ps[wave][fr][32 + ko];
    __builtin_amdgcn_s_setprio(1);
#pragma unroll
    for (int dt = 0; dt < 8; ++dt) {
      bf16x8 vf0 = *(const bf16x8*)&Vs[dt * 16 + fr][ko];
      bf16x8 vf1 = *(const bf16x8*)&Vs[dt * 16 + fr][32 + ko];
      o[dt] = MFMA16(pf0, vf0, o[dt]);
      o[dt] = MFMA16(pf1, vf1, o[dt]);
    }
    __builtin_amdgcn_s_setprio(0);

    __syncthreads();
    if (more) WRITETILE();
    __syncthreads();
  }

  if (!partial) {
    const float inv = 1.0f / lrun;
    float iv[4];
#pragma unroll
    for (int r = 0; r < 4; ++r) iv[r] = __shfl(inv, g4 + r, 64);
#pragma unroll
    for (int r = 0; r < 4; ++r) {
      const int qrow = q0 + wave * 16 + g4 + r;
#pragma unroll
      for (int dt = 0; dt < 8; ++dt)
        op[baseo + (size_t)qrow * DMODEL + dt * 16 + fr] = f2bf(o[dt][r] * iv[r]);
    }
  } else {
    const int sidx = (((b * 8 + (h >> 1)) * 16 + (qt - 16)) << 1) + part;
    const size_t sb = (size_t)sidx * 64;
#pragma unroll
    for (int r = 0; r < 4; ++r) {
      const size_t row = sb + wave * 16 + g4 + r;
#pragma unroll
      for (int dt = 0; dt < 8; ++dt)
        pO[row * HDIM + dt * 16 + fr] = f2bf(o[dt][r]);
    }
    if (lane < 16) {
      pm[sb + wave * 16 + lane] = mrun;
      pl[sb + wave * 16 + lane] = lrun;
    }
  }
}

// ---------------------------------------------------------------------------
// Merge two partials per (b, even h, qt>=16). Grid 256 blocks x 256 thr.
// ---------------------------------------------------------------------------
__global__ __launch_bounds__(256) void merge_kernel(const u16* __restrict__ pO,
                                                    const float* __restrict__ pm,
                                                    const float* __restrict__ pl,
                                                    u16* __restrict__ op) {
  const int x = blockIdx.x;
  const int qt16 = x & 15, eh = (x >> 4) & 7, b = x >> 7;
  const int h = eh * 2, qt = 16 + qt16;
  const int s0 = x * 2, s1 = s0 + 1;

  for (int i = 0; i < 4; ++i) {
    const int vidx = threadIdx.x + i * 256;
    const int row = vidx >> 4, d8 = (vidx & 15) * 8;
    const float m0 = pm[s0 * 64 + row], m1 = pm[s1 * 64 + row];
    const float l0 = pl[s0 * 64 + row], l1 = pl[s1 * 64 + row];
    const float m = fmaxf(m0, m1);
    const float w0 = __expf((m0 - m) * SC), w1 = __expf((m1 - m) * SC);
    const float inv = 1.0f / (l0 * w0 + l1 * w1);
    bf16x8 a = *(const bf16x8*)&pO[((size_t)s0 * 64 + row) * HDIM + d8];
    bf16x8 c = *(const bf16x8*)&pO[((size_t)s1 * 64 + row) * HDIM + d8];
    bf16x8 r;
#pragma unroll
    for (int j = 0; j < 8; ++j)
      r[j] = (short)f2bf((bf2f((u16)a[j]) * w0 + bf2f((u16)c[j]) * w1) * inv);
    *(bf16x8*)&op[((size_t)(b * T_SEQ + qt * 64 + row)) * DMODEL + h * HDIM + d8] = r;
  }
}

// ---------------------------------------------------------------------------
extern "C" void kernel_launch(void* const* d_in, const int* in_sizes, int n_in,
                              void* d_out, int out_size, void* d_ws, size_t ws_size,
                              hipStream_t stream) {
  (void)in_sizes; (void)n_in; (void)out_size; (void)ws_size;
  const float* x  = (const float*)d_in[0];
  const float* Wq = (const float*)d_in[1];
  const float* Wk = (const float*)d_in[2];
  const float* Wv = (const float*)d_in[3];
  const float* Wo = (const float*)d_in[4];

  const size_t NX = (size_t)MROWS * DMODEL;
  const size_t NW = (size_t)DMODEL * DMODEL;
  u16* ws  = (u16*)d_ws;
  u16* xb  = ws;                 // bf16 x; later attention output
  u16* wqb = ws + NX;            // [wq|wk|wv] contiguous = Wcat[6144][2048]
  u16* wkb = wqb + NW;
  u16* wvb = wkb + NW;
  u16* wob = wvb + NW;
  u16* qkb = wob + NW;                          // [4096][4096]
  u16* vtb = qkb + (size_t)MROWS * 2 * DMODEL;  // [32][128][2048]

  u16*   pO = wqb;                               // partials reuse dead wq/wk region
  float* pm = (float*)(wqb + (size_t)512 * 64 * HDIM);
  float* pl = pm + 512 * 64;

  convert_all<<<2048, 256, 0, stream>>>(x, Wq, Wk, Wv, Wo, ws);

  gemm_qkv<<<512, 512, 0, stream>>>(xb, wqb, qkb, vtb);

  attn_kernel<<<dim3(48, NHEADS, 2), 256, 0, stream>>>(qkb, vtb, xb, pO, pm, pl);

  merge_kernel<<<256, 256, 0, stream>>>(pO, pm, pl, xb);

  gemm_out<<<256, 512, 0, stream>>>(xb, wob, (float*)d_out);
}